// Round 9
// baseline (958.991 us; speedup 1.0000x reference)
//
#include <hip/hip_runtime.h>
#include <math.h>

// ---------------------------------------------------------------------------
// AttnJGNN: 3 iters of {intra-cluster GAT (MFMA bf16), dense Wo update,
// inter-cluster edge GAT}, then column means -> tiny MLP -> 1 scalar.
// R6 redesign of kAttn: S^T formulation keeps P entirely in registers
// (softmax + PV-fragment pack via shfl), VsT reuses G's LDS after a barrier.
// LDS 99840 -> 50688 B => 2 blocks/CU (was 1). Occupancy 11% -> ~22%.
// ---------------------------------------------------------------------------

typedef __attribute__((ext_vector_type(8))) short short8;
typedef __attribute__((ext_vector_type(4))) float floatx4;

__device__ __forceinline__ floatx4 mfma16(short8 a, short8 b, floatx4 c) {
  return __builtin_amdgcn_mfma_f32_16x16x32_bf16(a, b, c, 0, 0, 0);
}

__device__ __forceinline__ unsigned short f2b(float f) {  // f32 -> bf16 RTN
  union { float f; unsigned u; } x; x.f = f;
  return (unsigned short)((x.u + 0x7fffu + ((x.u >> 16) & 1u)) >> 16);
}
__device__ __forceinline__ float b2f(unsigned short b) {
  union { unsigned u; float f; } x; x.u = ((unsigned)b) << 16; return x.f;
}
__device__ __forceinline__ unsigned pk2(float lo, float hi) {
  return (unsigned)f2b(lo) | ((unsigned)f2b(hi) << 16);
}

// LDS bf16 tile fragment read: row-major, rowBytes stride, XOR-swizzled.
__device__ __forceinline__ short8 ldsFrag(const unsigned short* base, int row,
                                          int rowBytes, int byteInRow) {
  const char* b = (const char*)base;
  return *(const short8*)(b + row * rowBytes + (byteInRow ^ ((row & 7) << 4)));
}

struct __align__(16) SmemB {
  int ids[192];                    // 768 B
  float bias[192];                 // 768 B
  unsigned short xs[192 * 64];     // Xs[row][d] bf16, 128B rows, swizzled
  unsigned short gv[192 * 64];     // G[192][64] (ph2a..ph3) then VsT[64][192]
};                                 // total 50688 B -> 2 blocks/CU (VGPR<=256)

// ---- Intra-cluster attention: one block per cluster, 4 waves ---------------
__global__ __launch_bounds__(256, 2) void kAttn(
    const float* __restrict__ xv, const float* __restrict__ xc,
    const float* __restrict__ sat, const int* __restrict__ cvar,
    const int* __restrict__ ccla, const unsigned short* __restrict__ Bt,
    const unsigned short* __restrict__ WVb, float* __restrict__ outb,
    int N, int M) {
  __shared__ SmemB sm;
  const int c = blockIdx.x;
  const int tid = threadIdx.x;
  const int w = tid >> 6;
  const int l = tid & 63;
  const int l15 = l & 15;
  const int g = l >> 4;
  const int i0 = 48 * w;   // this wave's query-row block

  // phase 0: node ids + clause bias
  if (tid < 192) {
    int id; float bv;
    if (tid < 64) { id = cvar[c * 64 + tid]; bv = 0.f; }
    else { int cl = ccla[c * 128 + (tid - 64)]; id = N + cl; bv = 1.0f * sat[cl]; }
    sm.ids[tid] = id;
    sm.bias[tid] = bv;
  }
  __syncthreads();

  // phase 1: gather Xs (f32 global -> bf16 LDS, swizzled). 16 thr/row.
  {
    char* xsB = (char*)sm.xs;
#pragma unroll
    for (int ph = 0; ph < 12; ++ph) {
      int idx = ph * 256 + tid;
      int row = idx >> 4, sub = idx & 15;
      int id = sm.ids[row];
      const float* src =
          (id < N ? xv + (size_t)id * 64 : xc + (size_t)(id - N) * 64) + sub * 4;
      float4 v = *(const float4*)src;
      uint2 pkv; pkv.x = pk2(v.x, v.y); pkv.y = pk2(v.z, v.w);
      *(uint2*)(xsB + row * 128 + ((sub * 8) ^ ((row & 7) << 4))) = pkv;
    }
  }
  __syncthreads();

  // phase 2a: G = Xs @ B (own 48 rows) -> gv as G[192][64] swizzled
  {
    floatx4 ga[3][4];
#pragma unroll
    for (int a = 0; a < 3; ++a)
#pragma unroll
      for (int b = 0; b < 4; ++b) ga[a][b] = (floatx4)(0.f);
#pragma unroll
    for (int ks = 0; ks < 2; ++ks) {
      short8 af[3];
#pragma unroll
      for (int ti = 0; ti < 3; ++ti)
        af[ti] = ldsFrag(sm.xs, i0 + 16 * ti + l15, 128, ks * 64 + g * 16);
#pragma unroll
      for (int sp = 0; sp < 2; ++sp) {
        const unsigned short* bp = Bt + sp * 4096;
#pragma unroll
        for (int te = 0; te < 4; ++te) {
          short8 bf = *(const short8*)(bp + (16 * te + l15) * 64 + ks * 32 + g * 8);
#pragma unroll
          for (int ti = 0; ti < 3; ++ti) ga[ti][te] = mfma16(af[ti], bf, ga[ti][te]);
        }
      }
    }
    char* gB = (char*)sm.gv;
#pragma unroll
    for (int ti = 0; ti < 3; ++ti)
#pragma unroll
      for (int te = 0; te < 4; ++te)
#pragma unroll
        for (int r = 0; r < 4; ++r) {
          float x0 = ga[ti][te][r];
          float x1 = __shfl_xor(x0, 1);
          unsigned wp = (l & 1) ? pk2(x1, x0) : pk2(x0, x1);
          if ((l & 1) == (r >> 1)) {
            int i = i0 + 16 * ti + 4 * g + r;
            int eb = 16 * te + (l & 14);
            *(unsigned*)(gB + i * 128 + ((2 * eb) ^ ((i & 7) << 4))) = wp;
          }
        }
  }
  __syncthreads();

  // phase 3: S^T = mfma(A=Xs rows j, B=G rows i).
  // sc[tj][ti][r]: j = 16*tj + 4*g + r,  i = i0 + 16*ti + l15.
  floatx4 sc[12][3];
#pragma unroll
  for (int a = 0; a < 12; ++a)
#pragma unroll
    for (int b = 0; b < 3; ++b) sc[a][b] = (floatx4)(0.f);
#pragma unroll
  for (int ks = 0; ks < 2; ++ks) {
    short8 gb[3];
#pragma unroll
    for (int ti = 0; ti < 3; ++ti)
      gb[ti] = ldsFrag(sm.gv, i0 + 16 * ti + l15, 128, ks * 64 + g * 16);
#pragma unroll
    for (int tj = 0; tj < 12; ++tj) {
      short8 xa = ldsFrag(sm.xs, 16 * tj + l15, 128, ks * 64 + g * 16);
#pragma unroll
      for (int ti = 0; ti < 3; ++ti) sc[tj][ti] = mfma16(xa, gb[ti], sc[tj][ti]);
    }
  }

  // softmax fully in-register: row i = l15-group; j spread over {tj,r} x 4 g's
  {
#pragma unroll
    for (int ti = 0; ti < 3; ++ti) {
      float mx = -1e30f;
#pragma unroll
      for (int tj = 0; tj < 12; ++tj) {
        const float4 bq = *(const float4*)&sm.bias[16 * tj + 4 * g];
#pragma unroll
        for (int r = 0; r < 4; ++r) {
          float s = sc[tj][ti][r] + ((const float*)&bq)[r];
          s = s >= 0.f ? s : 0.2f * s;
          sc[tj][ti][r] = s;
          mx = fmaxf(mx, s);
        }
      }
      mx = fmaxf(mx, __shfl_xor(mx, 16));
      mx = fmaxf(mx, __shfl_xor(mx, 32));
      float sum = 0.f;
#pragma unroll
      for (int tj = 0; tj < 12; ++tj)
#pragma unroll
        for (int r = 0; r < 4; ++r) {
          float ev = __expf(sc[tj][ti][r] - mx);
          sc[tj][ti][r] = ev;
          sum += ev;
        }
      sum += __shfl_xor(sum, 16);
      sum += __shfl_xor(sum, 32);
      float rr = 1.0f / sum;
#pragma unroll
      for (int tj = 0; tj < 12; ++tj)
#pragma unroll
        for (int r = 0; r < 4; ++r) sc[tj][ti][r] *= rr;
    }
  }
  __syncthreads();   // all waves done reading gv-as-G

  // phase 2b': VsT = (hw1m*WV) @ Xs^T (own 48 cols) -> gv as VsT[64][192]
  {
    floatx4 va[4][3];
#pragma unroll
    for (int a = 0; a < 4; ++a)
#pragma unroll
      for (int b = 0; b < 3; ++b) va[a][b] = (floatx4)(0.f);
#pragma unroll
    for (int ks = 0; ks < 2; ++ks) {
      short8 xb[3];
#pragma unroll
      for (int tj = 0; tj < 3; ++tj)
        xb[tj] = ldsFrag(sm.xs, i0 + 16 * tj + l15, 128, ks * 64 + g * 16);
#pragma unroll
      for (int sp = 0; sp < 2; ++sp) {
        const unsigned short* wp2 = WVb + sp * 4096;
#pragma unroll
        for (int te = 0; te < 4; ++te) {
          short8 wa = *(const short8*)(wp2 + (16 * te + l15) * 64 + ks * 32 + g * 8);
#pragma unroll
          for (int tj = 0; tj < 3; ++tj) va[te][tj] = mfma16(wa, xb[tj], va[te][tj]);
        }
      }
    }
    char* vB = (char*)sm.gv;
#pragma unroll
    for (int te = 0; te < 4; ++te)
#pragma unroll
      for (int tj = 0; tj < 3; ++tj)
#pragma unroll
        for (int r = 0; r < 4; ++r) {
          float x0 = va[te][tj][r];
          float x1 = __shfl_xor(x0, 1);
          unsigned wp = (l & 1) ? pk2(x1, x0) : pk2(x0, x1);
          if ((l & 1) == (r >> 1)) {
            int e2 = 16 * te + 4 * g + r;
            int jb = i0 + 16 * tj + (l & 14);
            *(unsigned*)(vB + e2 * 384 + ((2 * jb) ^ ((e2 & 7) << 4))) = wp;
          }
        }
  }
  __syncthreads();

  // phase 4: h^T = VsT . P^T. A = VsT rows e (LDS), B = P rows i (registers,
  // packed from sc via pk2 + shfl). C: rows e = 4g+r, cols i = l15.
  {
    floatx4 hacc[4][3];
#pragma unroll
    for (int a = 0; a < 4; ++a)
#pragma unroll
      for (int b = 0; b < 3; ++b) hacc[a][b] = (floatx4)(0.f);
    const char* vB = (const char*)sm.gv;
#pragma unroll
    for (int ksj = 0; ksj < 6; ++ksj) {
      short8 av[4];
#pragma unroll
      for (int te = 0; te < 4; ++te) {
        int e2 = 16 * te + l15;
        av[te] = *(const short8*)(vB + e2 * 384 + ((ksj * 64 + 16 * g) ^ ((e2 & 7) << 4)));
      }
#pragma unroll
      for (int ti = 0; ti < 3; ++ti) {
        // pack this lane's P j-pairs for the two tj blocks of this k-slice
        unsigned pw00 = pk2(sc[2 * ksj][ti][0], sc[2 * ksj][ti][1]);
        unsigned pw01 = pk2(sc[2 * ksj][ti][2], sc[2 * ksj][ti][3]);
        unsigned pw10 = pk2(sc[2 * ksj + 1][ti][0], sc[2 * ksj + 1][ti][1]);
        unsigned pw11 = pk2(sc[2 * ksj + 1][ti][2], sc[2 * ksj + 1][ti][3]);
        // gather B-frag words: lane g needs j = 32ksj + 8g + [0..8)
        union { unsigned u[4]; short8 s8; } pbu;
#pragma unroll
        for (int w2 = 0; w2 < 4; ++w2) {
          int src = 16 * (((g & 1) << 1) + (w2 >> 1)) + l15;
          unsigned wa = __shfl((w2 & 1) ? pw01 : pw00, src);
          unsigned wb = __shfl((w2 & 1) ? pw11 : pw10, src);
          pbu.u[w2] = (g >> 1) ? wb : wa;
        }
#pragma unroll
        for (int te = 0; te < 4; ++te)
          hacc[te][ti] = mfma16(av[te], pbu.s8, hacc[te][ti]);
      }
    }
    // scatter: lane l15 -> query i (node); e = 16te + 4g + r
#pragma unroll
    for (int ti = 0; ti < 3; ++ti) {
      int i = i0 + 16 * ti + l15;
      int node = sm.ids[i];
      float* dst = outb + (size_t)node * 64;
#pragma unroll
      for (int te = 0; te < 4; ++te)
#pragma unroll
        for (int r = 0; r < 4; ++r)
          atomicAdd(dst + 16 * te + 4 * g + r, hacc[te][ti][r]);
    }
  }
}

// ---- x += (out/max(cnt,1)) @ Wo^T + bo; also re-zero `out` ------------------
__global__ __launch_bounds__(256) void kUpd(
    float* __restrict__ xv, float* __restrict__ xc,
    const float* __restrict__ bo, const unsigned short* __restrict__ WoB,
    float* __restrict__ outb, const float* __restrict__ cnt, int NM, int N) {
  const int tid = threadIdx.x;
  const int w = tid >> 6, l = tid & 63, l15 = l & 15, g = l >> 4;
  const int rb = blockIdx.x * 128;
  const int r0 = rb + 32 * w;
  floatx4 acc[2][4];
#pragma unroll
  for (int a = 0; a < 2; ++a)
#pragma unroll
    for (int b = 0; b < 4; ++b) acc[a][b] = (floatx4)(0.f);
#pragma unroll
  for (int ks = 0; ks < 2; ++ks) {
    short8 af[2];
#pragma unroll
    for (int ti = 0; ti < 2; ++ti) {
      int r = r0 + 16 * ti + l15;
      float4 v0 = {0.f, 0.f, 0.f, 0.f}, v1 = {0.f, 0.f, 0.f, 0.f};
      float inv = 0.f;
      if (r < NM) {
        inv = 1.0f / fmaxf(cnt[r], 1.0f);
        const float4* s4 = (const float4*)(outb + (size_t)r * 64 + ks * 32 + g * 8);
        v0 = s4[0]; v1 = s4[1];
      }
      short8 a;
      a[0] = (short)f2b(v0.x * inv); a[1] = (short)f2b(v0.y * inv);
      a[2] = (short)f2b(v0.z * inv); a[3] = (short)f2b(v0.w * inv);
      a[4] = (short)f2b(v1.x * inv); a[5] = (short)f2b(v1.y * inv);
      a[6] = (short)f2b(v1.z * inv); a[7] = (short)f2b(v1.w * inv);
      af[ti] = a;
    }
#pragma unroll
    for (int sp = 0; sp < 2; ++sp) {
      const unsigned short* wp = WoB + sp * 4096;
#pragma unroll
      for (int te = 0; te < 4; ++te) {
        short8 bf = *(const short8*)(wp + (16 * te + l15) * 64 + ks * 32 + g * 8);
#pragma unroll
        for (int ti = 0; ti < 2; ++ti) acc[ti][te] = mfma16(af[ti], bf, acc[ti][te]);
      }
    }
  }
#pragma unroll
  for (int ti = 0; ti < 2; ++ti)
#pragma unroll
    for (int r = 0; r < 4; ++r) {
      int row = r0 + 16 * ti + 4 * g + r;
      if (row < NM) {
        float* xp = (row < N) ? (xv + (size_t)row * 64) : (xc + (size_t)(row - N) * 64);
#pragma unroll
        for (int te = 0; te < 4; ++te) {
          int e2 = 16 * te + l15;
          xp[e2] += acc[ti][te][r] + bo[e2];
        }
      }
    }
  // zero this block's `out` slab for the next iteration
  const float4 z = {0.f, 0.f, 0.f, 0.f};
  for (int q = tid; q < 2048; q += 256) {
    int row = rb + (q >> 4);
    if (row < NM) *(float4*)(outb + (size_t)rb * 64 + q * 4) = z;
  }
}

// ---- cluster features + Q2/K2/V2 -------------------------------------------
__global__ __launch_bounds__(64) void kCf(
    const float* __restrict__ xv, const int* __restrict__ cvar,
    const float* __restrict__ WQ2T, const float* __restrict__ WK2T,
    const float* __restrict__ WV2T, float* __restrict__ Q2,
    float* __restrict__ K2, float* __restrict__ V2) {
  __shared__ float cfs[64];
  const int c = blockIdx.x, l = threadIdx.x;
  float acc = 0.f;
#pragma unroll 8
  for (int v = 0; v < 64; ++v) acc += xv[(size_t)cvar[c * 64 + v] * 64 + l];
  cfs[l] = acc * 0.015625f;
  __syncthreads();
  float q = 0.f, k = 0.f, vv = 0.f;
#pragma unroll 8
  for (int d = 0; d < 64; ++d) {
    float cd = cfs[d];
    q += cd * WQ2T[d * 64 + l];
    k += cd * WK2T[d * 64 + l];
    vv += cd * WV2T[d * 64 + l];
  }
  Q2[c * 64 + l] = q; K2[c * 64 + l] = k; V2[c * 64 + l] = vv;
}

// ---- per-edge scalar attention + scatter into shared vars ------------------
__global__ __launch_bounds__(256) void kEdge(
    float* __restrict__ xv, const float* __restrict__ Q2,
    const float* __restrict__ K2, const float* __restrict__ V2,
    const int* __restrict__ eidx, const int* __restrict__ shv,
    const float* __restrict__ hw2m, int E_) {
  const int e = blockIdx.x * 4 + (threadIdx.x >> 6);
  const int l = threadIdx.x & 63;
  if (e >= E_) return;
  const int c1 = eidx[e], c2 = eidx[E_ + e];
  float p = Q2[c1 * 64 + l] * K2[c2 * 64 + l];
#pragma unroll
  for (int mk = 32; mk >= 1; mk >>= 1) p += __shfl_xor(p, mk);
  float s = p * 0.125f;
  s = s >= 0.f ? s : 0.2f * s;
  float a = hw2m[0] / (1.f + __expf(-s));
  float val = V2[c2 * 64 + l] * a;
#pragma unroll
  for (int t = 0; t < 8; ++t) {
    int row = shv[e * 8 + t];
    atomicAdd(xv + (size_t)row * 64 + l, val);
  }
}

// ---- column sums of x_var / x_clause ---------------------------------------
__global__ __launch_bounds__(256) void kSum(
    const float* __restrict__ xv, const float* __restrict__ xc,
    float* __restrict__ sums, int N, int M) {
  __shared__ float red[4][128];
  const int tid = threadIdx.x, w = tid >> 6, l = tid & 63;
  const int gw = (blockIdx.x * 256 + tid) >> 6;
  const int nw = (gridDim.x * 256) >> 6;
  float aV = 0.f, aC = 0.f;
  for (int r = gw; r < N + M; r += nw) {
    if (r < N) aV += xv[(size_t)r * 64 + l];
    else aC += xc[(size_t)(r - N) * 64 + l];
  }
  red[w][l] = aV; red[w][64 + l] = aC;
  __syncthreads();
  if (tid < 128) {
    float v = red[0][tid] + red[1][tid] + red[2][tid] + red[3][tid];
    atomicAdd(&sums[tid], v);
  }
}

// ---- pooled -> MLP -> scalar ------------------------------------------------
__global__ __launch_bounds__(128) void kMlp(
    const float* __restrict__ sums, const float* __restrict__ W1,
    const float* __restrict__ b1, const float* __restrict__ W2,
    const float* __restrict__ b2, float* __restrict__ outp, int N, int M) {
  __shared__ float pooled[128];
  __shared__ float hs[64];
  const int t = threadIdx.x;
  pooled[t] = tanhf(sums[t] * (t < 64 ? 1.f / (float)N : 1.f / (float)M));
  __syncthreads();
  if (t < 64) {
    float a = b1[t];
#pragma unroll 8
    for (int j = 0; j < 128; ++j) a += W1[t * 128 + j] * pooled[j];
    hs[t] = fmaxf(a, 0.f);
  }
  __syncthreads();
  if (t < 64) {
    float v = W2[t] * hs[t];
#pragma unroll
    for (int mk = 32; mk >= 1; mk >>= 1) v += __shfl_xor(v, mk);
    if (t == 0) outp[0] = v + b2[0];
  }
}

// ---- precompute: B^T (stored [e][d]), hw1*WV, Wo (hi/lo bf16),
//      W*2 transposes, hw2 mean --------------------------------------------
__global__ __launch_bounds__(256) void kPrep(
    const float* __restrict__ WQ1, const float* __restrict__ WK1,
    const float* __restrict__ WV1, const float* __restrict__ hw1,
    const float* __restrict__ Wo, const float* __restrict__ WQ2,
    const float* __restrict__ WK2, const float* __restrict__ WV2,
    const float* __restrict__ hw2, unsigned short* __restrict__ Bt,
    unsigned short* __restrict__ WVb, unsigned short* __restrict__ WoB,
    float* __restrict__ WQ2T, float* __restrict__ WK2T,
    float* __restrict__ WV2T, float* __restrict__ hw2m) {
  __shared__ float Qs[64][65];
  __shared__ float Ks[64][65];
  const int t = threadIdx.x;
  for (int i = t; i < 4096; i += 256) {
    Qs[i >> 6][i & 63] = WQ1[i];
    Ks[i >> 6][i & 63] = WK1[i];
  }
  const float h1m = 0.25f * (hw1[0] + hw1[1] + hw1[2] + hw1[3]);
  __syncthreads();
  for (int o = t; o < 4096; o += 256) {
    const int eo = o >> 6, d = o & 63;
    float acc = 0.f;
#pragma unroll 8
    for (int a2 = 0; a2 < 64; ++a2) acc += Qs[a2][d] * Ks[a2][eo];
    acc *= 0.125f;  // /sqrt(64)
    unsigned short hi = f2b(acc);
    Bt[o] = hi; Bt[4096 + o] = f2b(acc - b2f(hi));
    float wv = WV1[o] * h1m;
    hi = f2b(wv); WVb[o] = hi; WVb[4096 + o] = f2b(wv - b2f(hi));
    float wo = Wo[o];
    hi = f2b(wo); WoB[o] = hi; WoB[4096 + o] = f2b(wo - b2f(hi));
    const int tr = ((o & 63) << 6) | (o >> 6);
    WQ2T[o] = WQ2[tr]; WK2T[o] = WK2[tr]; WV2T[o] = WV2[tr];
  }
  if (t == 0) hw2m[0] = 0.25f * (hw2[0] + hw2[1] + hw2[2] + hw2[3]);
}

// ---- node occurrence counts (static across iterations) ---------------------
__global__ __launch_bounds__(256) void kCnt(
    const int* __restrict__ cvar, const int* __restrict__ ccla,
    float* __restrict__ cnt, int C_, int N) {
  int i = blockIdx.x * 256 + threadIdx.x;
  const int T = C_ * 192;
  for (; i < T; i += gridDim.x * 256) {
    int c = i / 192, p = i - c * 192;
    int node = (p < 64) ? cvar[c * 64 + p] : (N + ccla[c * 128 + (p - 64)]);
    atomicAdd(cnt + node, 1.0f);
  }
}

extern "C" void kernel_launch(void* const* d_in, const int* in_sizes, int n_in,
                              void* d_out, int out_size, void* d_ws, size_t ws_size,
                              hipStream_t stream) {
  (void)n_in; (void)out_size;
  float* xv = (float*)d_in[0];
  float* xc = (float*)d_in[1];
  const float* sat = (const float*)d_in[2];
  const int* cvar = (const int*)d_in[3];
  const int* ccla = (const int*)d_in[4];
  const int* eidx = (const int*)d_in[5];
  const int* shv = (const int*)d_in[6];
  const float* WQ1 = (const float*)d_in[7];
  const float* WK1 = (const float*)d_in[8];
  const float* WV1 = (const float*)d_in[9];
  const float* hw1 = (const float*)d_in[10];
  const float* Wo = (const float*)d_in[11];
  const float* bo = (const float*)d_in[12];
  const float* WQ2 = (const float*)d_in[13];
  const float* WK2 = (const float*)d_in[14];
  const float* WV2 = (const float*)d_in[15];
  const float* hw2 = (const float*)d_in[16];
  const float* W1 = (const float*)d_in[17];
  const float* b1 = (const float*)d_in[18];
  const float* W2 = (const float*)d_in[19];
  const float* b2 = (const float*)d_in[20];

  const int N = in_sizes[0] / 64;
  const int M = in_sizes[1] / 64;
  const int C = in_sizes[3] / 64;
  const int E = in_sizes[5] / 2;
  const int NM = N + M;

  // Workspace guard: undersized d_ws -> no-op (clean failure, no OOB fault).
  size_t need = 0;
  auto sz = [&](size_t bytes) { need += (bytes + 255) & ~(size_t)255; };
  sz((size_t)NM * 64 * 4);  // outb
  sz((size_t)NM * 4);       // cnt
  sz(2 * 4096 * 2); sz(2 * 4096 * 2); sz(2 * 4096 * 2);   // Bt, WVb, WoB
  sz(4096 * 4); sz(4096 * 4); sz(4096 * 4);               // WQ2T, WK2T, WV2T
  sz((size_t)C * 64 * 4); sz((size_t)C * 64 * 4); sz((size_t)C * 64 * 4);
  sz(128 * 4); sz(256);                                   // sums, hw2m
  if (need > ws_size) return;

  char* p = (char*)d_ws;
  auto alloc = [&](size_t bytes) -> void* {
    void* r = (void*)p;
    p += (bytes + 255) & ~(size_t)255;
    return r;
  };
  float* outb = (float*)alloc((size_t)NM * 64 * 4);
  float* cnt = (float*)alloc((size_t)NM * 4);
  unsigned short* Bt = (unsigned short*)alloc(2 * 4096 * 2);
  unsigned short* WVb = (unsigned short*)alloc(2 * 4096 * 2);
  unsigned short* WoB = (unsigned short*)alloc(2 * 4096 * 2);
  float* WQ2T = (float*)alloc(4096 * 4);
  float* WK2T = (float*)alloc(4096 * 4);
  float* WV2T = (float*)alloc(4096 * 4);
  float* Q2 = (float*)alloc((size_t)C * 64 * 4);
  float* K2 = (float*)alloc((size_t)C * 64 * 4);
  float* V2 = (float*)alloc((size_t)C * 64 * 4);
  float* sums = (float*)alloc(128 * 4);
  float* hw2m = (float*)alloc(256);

  hipMemsetAsync(outb, 0, (size_t)NM * 64 * 4, stream);
  hipMemsetAsync(cnt, 0, (size_t)NM * 4, stream);
  hipMemsetAsync(sums, 0, 128 * 4, stream);

  kPrep<<<1, 256, 0, stream>>>(WQ1, WK1, WV1, hw1, Wo, WQ2, WK2, WV2, hw2,
                               Bt, WVb, WoB, WQ2T, WK2T, WV2T, hw2m);
  kCnt<<<256, 256, 0, stream>>>(cvar, ccla, cnt, C, N);

  for (int it = 0; it < 3; ++it) {
    kAttn<<<C, 256, 0, stream>>>(xv, xc, sat, cvar, ccla, Bt, WVb, outb, N, M);
    kUpd<<<(NM + 127) / 128, 256, 0, stream>>>(xv, xc, bo, WoB, outb, cnt, NM, N);
    kCf<<<C, 64, 0, stream>>>(xv, cvar, WQ2T, WK2T, WV2T, Q2, K2, V2);
    kEdge<<<(E + 3) / 4, 256, 0, stream>>>(xv, Q2, K2, V2, eidx, shv, hw2m, E);
  }

  kSum<<<1024, 256, 0, stream>>>(xv, xc, sums, N, M);
  kMlp<<<1, 128, 0, stream>>>(sums, W1, b1, W2, b2, (float*)d_out, N, M);
}

// Round 11
// 604.736 us; speedup vs baseline: 1.5858x; 1.5858x over previous
//
#include <hip/hip_runtime.h>
#include <math.h>

// ---------------------------------------------------------------------------
// AttnJGNN: 3 iters of {intra-cluster GAT (MFMA bf16), dense Wo update,
// inter-cluster edge GAT}, then column means -> tiny MLP -> 1 scalar.
// R9: phase-4 operand swap — mfma(A=P-pack, B=VsT-frag) gives h (not h^T),
// so the atomic scatter reverts to R0's coalesced 16-consecutive-dword
// pattern. Fixes R6's 4x WRITE_SIZE amplification (192MB -> 48MB/dispatch).
// Keeps R6's LDS diet: 50688 B => 2 blocks/CU, P in registers.
// ---------------------------------------------------------------------------

typedef __attribute__((ext_vector_type(8))) short short8;
typedef __attribute__((ext_vector_type(4))) float floatx4;

__device__ __forceinline__ floatx4 mfma16(short8 a, short8 b, floatx4 c) {
  return __builtin_amdgcn_mfma_f32_16x16x32_bf16(a, b, c, 0, 0, 0);
}

__device__ __forceinline__ unsigned short f2b(float f) {  // f32 -> bf16 RTN
  union { float f; unsigned u; } x; x.f = f;
  return (unsigned short)((x.u + 0x7fffu + ((x.u >> 16) & 1u)) >> 16);
}
__device__ __forceinline__ float b2f(unsigned short b) {
  union { unsigned u; float f; } x; x.u = ((unsigned)b) << 16; return x.f;
}
__device__ __forceinline__ unsigned pk2(float lo, float hi) {
  return (unsigned)f2b(lo) | ((unsigned)f2b(hi) << 16);
}

// LDS bf16 tile fragment read: row-major, rowBytes stride, XOR-swizzled.
__device__ __forceinline__ short8 ldsFrag(const unsigned short* base, int row,
                                          int rowBytes, int byteInRow) {
  const char* b = (const char*)base;
  return *(const short8*)(b + row * rowBytes + (byteInRow ^ ((row & 7) << 4)));
}

struct __align__(16) SmemB {
  int ids[192];                    // 768 B
  float bias[192];                 // 768 B
  unsigned short xs[192 * 64];     // Xs[row][d] bf16, 128B rows, swizzled
  unsigned short gv[192 * 64];     // G[192][64] (ph2a..ph3) then VsT[64][192]
};                                 // total 50688 B -> 2 blocks/CU

// ---- Intra-cluster attention: one block per cluster, 4 waves ---------------
__global__ __launch_bounds__(256, 2) void kAttn(
    const float* __restrict__ xv, const float* __restrict__ xc,
    const float* __restrict__ sat, const int* __restrict__ cvar,
    const int* __restrict__ ccla, const unsigned short* __restrict__ Bt,
    const unsigned short* __restrict__ WVb, float* __restrict__ outb,
    int N, int M) {
  __shared__ SmemB sm;
  const int c = blockIdx.x;
  const int tid = threadIdx.x;
  const int w = tid >> 6;
  const int l = tid & 63;
  const int l15 = l & 15;
  const int g = l >> 4;
  const int i0 = 48 * w;   // this wave's query-row block

  // phase 0: node ids + clause bias
  if (tid < 192) {
    int id; float bv;
    if (tid < 64) { id = cvar[c * 64 + tid]; bv = 0.f; }
    else { int cl = ccla[c * 128 + (tid - 64)]; id = N + cl; bv = 1.0f * sat[cl]; }
    sm.ids[tid] = id;
    sm.bias[tid] = bv;
  }
  __syncthreads();

  // phase 1: gather Xs (f32 global -> bf16 LDS, swizzled). 16 thr/row.
  {
    char* xsB = (char*)sm.xs;
#pragma unroll
    for (int ph = 0; ph < 12; ++ph) {
      int idx = ph * 256 + tid;
      int row = idx >> 4, sub = idx & 15;
      int id = sm.ids[row];
      const float* src =
          (id < N ? xv + (size_t)id * 64 : xc + (size_t)(id - N) * 64) + sub * 4;
      float4 v = *(const float4*)src;
      uint2 pkv; pkv.x = pk2(v.x, v.y); pkv.y = pk2(v.z, v.w);
      *(uint2*)(xsB + row * 128 + ((sub * 8) ^ ((row & 7) << 4))) = pkv;
    }
  }
  __syncthreads();

  // phase 2a: G = Xs @ B (own 48 rows) -> gv as G[192][64] swizzled
  {
    floatx4 ga[3][4];
#pragma unroll
    for (int a = 0; a < 3; ++a)
#pragma unroll
      for (int b = 0; b < 4; ++b) ga[a][b] = (floatx4)(0.f);
#pragma unroll
    for (int ks = 0; ks < 2; ++ks) {
      short8 af[3];
#pragma unroll
      for (int ti = 0; ti < 3; ++ti)
        af[ti] = ldsFrag(sm.xs, i0 + 16 * ti + l15, 128, ks * 64 + g * 16);
#pragma unroll
      for (int sp = 0; sp < 2; ++sp) {
        const unsigned short* bp = Bt + sp * 4096;
#pragma unroll
        for (int te = 0; te < 4; ++te) {
          short8 bf = *(const short8*)(bp + (16 * te + l15) * 64 + ks * 32 + g * 8);
#pragma unroll
          for (int ti = 0; ti < 3; ++ti) ga[ti][te] = mfma16(af[ti], bf, ga[ti][te]);
        }
      }
    }
    char* gB = (char*)sm.gv;
#pragma unroll
    for (int ti = 0; ti < 3; ++ti)
#pragma unroll
      for (int te = 0; te < 4; ++te)
#pragma unroll
        for (int r = 0; r < 4; ++r) {
          float x0 = ga[ti][te][r];
          float x1 = __shfl_xor(x0, 1);
          unsigned wp = (l & 1) ? pk2(x1, x0) : pk2(x0, x1);
          if ((l & 1) == (r >> 1)) {
            int i = i0 + 16 * ti + 4 * g + r;
            int eb = 16 * te + (l & 14);
            *(unsigned*)(gB + i * 128 + ((2 * eb) ^ ((i & 7) << 4))) = wp;
          }
        }
  }
  __syncthreads();

  // phase 3: S^T = mfma(A=Xs rows j, B=G rows i).
  // sc[tj][ti][r]: j = 16*tj + 4*g + r,  i = i0 + 16*ti + l15.
  floatx4 sc[12][3];
#pragma unroll
  for (int a = 0; a < 12; ++a)
#pragma unroll
    for (int b = 0; b < 3; ++b) sc[a][b] = (floatx4)(0.f);
#pragma unroll
  for (int ks = 0; ks < 2; ++ks) {
    short8 gb[3];
#pragma unroll
    for (int ti = 0; ti < 3; ++ti)
      gb[ti] = ldsFrag(sm.gv, i0 + 16 * ti + l15, 128, ks * 64 + g * 16);
#pragma unroll
    for (int tj = 0; tj < 12; ++tj) {
      short8 xa = ldsFrag(sm.xs, 16 * tj + l15, 128, ks * 64 + g * 16);
#pragma unroll
      for (int ti = 0; ti < 3; ++ti) sc[tj][ti] = mfma16(xa, gb[ti], sc[tj][ti]);
    }
  }

  // softmax fully in-register: row i = l15-group; j spread over {tj,r} x 4 g's
  {
#pragma unroll
    for (int ti = 0; ti < 3; ++ti) {
      float mx = -1e30f;
#pragma unroll
      for (int tj = 0; tj < 12; ++tj) {
        const float4 bq = *(const float4*)&sm.bias[16 * tj + 4 * g];
#pragma unroll
        for (int r = 0; r < 4; ++r) {
          float s = sc[tj][ti][r] + ((const float*)&bq)[r];
          s = s >= 0.f ? s : 0.2f * s;
          sc[tj][ti][r] = s;
          mx = fmaxf(mx, s);
        }
      }
      mx = fmaxf(mx, __shfl_xor(mx, 16));
      mx = fmaxf(mx, __shfl_xor(mx, 32));
      float sum = 0.f;
#pragma unroll
      for (int tj = 0; tj < 12; ++tj)
#pragma unroll
        for (int r = 0; r < 4; ++r) {
          float ev = __expf(sc[tj][ti][r] - mx);
          sc[tj][ti][r] = ev;
          sum += ev;
        }
      sum += __shfl_xor(sum, 16);
      sum += __shfl_xor(sum, 32);
      float rr = 1.0f / sum;
#pragma unroll
      for (int tj = 0; tj < 12; ++tj)
#pragma unroll
        for (int r = 0; r < 4; ++r) sc[tj][ti][r] *= rr;
    }
  }
  __syncthreads();   // all waves done reading gv-as-G

  // phase 2b': VsT = (hw1m*WV) @ Xs^T (own 48 cols) -> gv as VsT[64][192]
  {
    floatx4 va[4][3];
#pragma unroll
    for (int a = 0; a < 4; ++a)
#pragma unroll
      for (int b = 0; b < 3; ++b) va[a][b] = (floatx4)(0.f);
#pragma unroll
    for (int ks = 0; ks < 2; ++ks) {
      short8 xb[3];
#pragma unroll
      for (int tj = 0; tj < 3; ++tj)
        xb[tj] = ldsFrag(sm.xs, i0 + 16 * tj + l15, 128, ks * 64 + g * 16);
#pragma unroll
      for (int sp = 0; sp < 2; ++sp) {
        const unsigned short* wp2 = WVb + sp * 4096;
#pragma unroll
        for (int te = 0; te < 4; ++te) {
          short8 wa = *(const short8*)(wp2 + (16 * te + l15) * 64 + ks * 32 + g * 8);
#pragma unroll
          for (int tj = 0; tj < 3; ++tj) va[te][tj] = mfma16(wa, xb[tj], va[te][tj]);
        }
      }
    }
    char* vB = (char*)sm.gv;
#pragma unroll
    for (int te = 0; te < 4; ++te)
#pragma unroll
      for (int tj = 0; tj < 3; ++tj)
#pragma unroll
        for (int r = 0; r < 4; ++r) {
          float x0 = va[te][tj][r];
          float x1 = __shfl_xor(x0, 1);
          unsigned wp = (l & 1) ? pk2(x1, x0) : pk2(x0, x1);
          if ((l & 1) == (r >> 1)) {
            int e2 = 16 * te + 4 * g + r;
            int jb = i0 + 16 * tj + (l & 14);
            *(unsigned*)(vB + e2 * 384 + ((2 * jb) ^ ((e2 & 7) << 4))) = wp;
          }
        }
  }
  __syncthreads();

  // phase 4: h = P @ Vs. A = P rows i (registers, packed from sc via
  // pk2 + shfl; A/B fragments share the same lane layout). B = VsT rows e
  // (LDS). C: rows i = 4g+r, cols e = l15 -> R0-style coalesced scatter.
  {
    floatx4 hacc[3][4];   // [ti][te], reg r: i = i0+16ti+4g+r, e = 16te+l15
#pragma unroll
    for (int a = 0; a < 3; ++a)
#pragma unroll
      for (int b = 0; b < 4; ++b) hacc[a][b] = (floatx4)(0.f);
    const char* vB = (const char*)sm.gv;
#pragma unroll
    for (int ksj = 0; ksj < 6; ++ksj) {
      short8 bv[4];
#pragma unroll
      for (int te = 0; te < 4; ++te) {
        int e2 = 16 * te + l15;
        bv[te] = *(const short8*)(vB + e2 * 384 + ((ksj * 64 + 16 * g) ^ ((e2 & 7) << 4)));
      }
#pragma unroll
      for (int ti = 0; ti < 3; ++ti) {
        // pack this lane's P j-pairs for the two tj blocks of this k-slice
        unsigned pw00 = pk2(sc[2 * ksj][ti][0], sc[2 * ksj][ti][1]);
        unsigned pw01 = pk2(sc[2 * ksj][ti][2], sc[2 * ksj][ti][3]);
        unsigned pw10 = pk2(sc[2 * ksj + 1][ti][0], sc[2 * ksj + 1][ti][1]);
        unsigned pw11 = pk2(sc[2 * ksj + 1][ti][2], sc[2 * ksj + 1][ti][3]);
        // gather A-frag words: lane g needs j = 32ksj + 8g + [0..8), row=l15
        union { unsigned u[4]; short8 s8; } pbu;
#pragma unroll
        for (int w2 = 0; w2 < 4; ++w2) {
          int src = 16 * (((g & 1) << 1) + (w2 >> 1)) + l15;
          unsigned wa = __shfl((w2 & 1) ? pw01 : pw00, src);
          unsigned wb = __shfl((w2 & 1) ? pw11 : pw10, src);
          pbu.u[w2] = (g >> 1) ? wb : wa;
        }
#pragma unroll
        for (int te = 0; te < 4; ++te)
          hacc[ti][te] = mfma16(pbu.s8, bv[te], hacc[ti][te]);
      }
    }
    // scatter (R0 pattern): per (ti,r) the 16 lanes of group g write 16
    // consecutive dwords of one node row per te -> full line merging.
#pragma unroll
    for (int ti = 0; ti < 3; ++ti)
#pragma unroll
      for (int r = 0; r < 4; ++r) {
        int i = i0 + 16 * ti + 4 * g + r;
        int node = sm.ids[i];
        float* dst = outb + (size_t)node * 64;
#pragma unroll
        for (int te = 0; te < 4; ++te)
          atomicAdd(dst + 16 * te + l15, hacc[ti][te][r]);
      }
  }
}

// ---- x += (out/max(cnt,1)) @ Wo^T + bo; also re-zero `out` ------------------
__global__ __launch_bounds__(256) void kUpd(
    float* __restrict__ xv, float* __restrict__ xc,
    const float* __restrict__ bo, const unsigned short* __restrict__ WoB,
    float* __restrict__ outb, const float* __restrict__ cnt, int NM, int N) {
  const int tid = threadIdx.x;
  const int w = tid >> 6, l = tid & 63, l15 = l & 15, g = l >> 4;
  const int rb = blockIdx.x * 128;
  const int r0 = rb + 32 * w;
  floatx4 acc[2][4];
#pragma unroll
  for (int a = 0; a < 2; ++a)
#pragma unroll
    for (int b = 0; b < 4; ++b) acc[a][b] = (floatx4)(0.f);
#pragma unroll
  for (int ks = 0; ks < 2; ++ks) {
    short8 af[2];
#pragma unroll
    for (int ti = 0; ti < 2; ++ti) {
      int r = r0 + 16 * ti + l15;
      float4 v0 = {0.f, 0.f, 0.f, 0.f}, v1 = {0.f, 0.f, 0.f, 0.f};
      float inv = 0.f;
      if (r < NM) {
        inv = 1.0f / fmaxf(cnt[r], 1.0f);
        const float4* s4 = (const float4*)(outb + (size_t)r * 64 + ks * 32 + g * 8);
        v0 = s4[0]; v1 = s4[1];
      }
      short8 a;
      a[0] = (short)f2b(v0.x * inv); a[1] = (short)f2b(v0.y * inv);
      a[2] = (short)f2b(v0.z * inv); a[3] = (short)f2b(v0.w * inv);
      a[4] = (short)f2b(v1.x * inv); a[5] = (short)f2b(v1.y * inv);
      a[6] = (short)f2b(v1.z * inv); a[7] = (short)f2b(v1.w * inv);
      af[ti] = a;
    }
#pragma unroll
    for (int sp = 0; sp < 2; ++sp) {
      const unsigned short* wp = WoB + sp * 4096;
#pragma unroll
      for (int te = 0; te < 4; ++te) {
        short8 bf = *(const short8*)(wp + (16 * te + l15) * 64 + ks * 32 + g * 8);
#pragma unroll
        for (int ti = 0; ti < 2; ++ti) acc[ti][te] = mfma16(af[ti], bf, acc[ti][te]);
      }
    }
  }
#pragma unroll
  for (int ti = 0; ti < 2; ++ti)
#pragma unroll
    for (int r = 0; r < 4; ++r) {
      int row = r0 + 16 * ti + 4 * g + r;
      if (row < NM) {
        float* xp = (row < N) ? (xv + (size_t)row * 64) : (xc + (size_t)(row - N) * 64);
#pragma unroll
        for (int te = 0; te < 4; ++te) {
          int e2 = 16 * te + l15;
          xp[e2] += acc[ti][te][r] + bo[e2];
        }
      }
    }
  // zero this block's `out` slab for the next iteration
  const float4 z = {0.f, 0.f, 0.f, 0.f};
  for (int q = tid; q < 2048; q += 256) {
    int row = rb + (q >> 4);
    if (row < NM) *(float4*)(outb + (size_t)rb * 64 + q * 4) = z;
  }
}

// ---- cluster features + Q2/K2/V2 -------------------------------------------
__global__ __launch_bounds__(64) void kCf(
    const float* __restrict__ xv, const int* __restrict__ cvar,
    const float* __restrict__ WQ2T, const float* __restrict__ WK2T,
    const float* __restrict__ WV2T, float* __restrict__ Q2,
    float* __restrict__ K2, float* __restrict__ V2) {
  __shared__ float cfs[64];
  const int c = blockIdx.x, l = threadIdx.x;
  float acc = 0.f;
#pragma unroll 8
  for (int v = 0; v < 64; ++v) acc += xv[(size_t)cvar[c * 64 + v] * 64 + l];
  cfs[l] = acc * 0.015625f;
  __syncthreads();
  float q = 0.f, k = 0.f, vv = 0.f;
#pragma unroll 8
  for (int d = 0; d < 64; ++d) {
    float cd = cfs[d];
    q += cd * WQ2T[d * 64 + l];
    k += cd * WK2T[d * 64 + l];
    vv += cd * WV2T[d * 64 + l];
  }
  Q2[c * 64 + l] = q; K2[c * 64 + l] = k; V2[c * 64 + l] = vv;
}

// ---- per-edge scalar attention + scatter into shared vars ------------------
__global__ __launch_bounds__(256) void kEdge(
    float* __restrict__ xv, const float* __restrict__ Q2,
    const float* __restrict__ K2, const float* __restrict__ V2,
    const int* __restrict__ eidx, const int* __restrict__ shv,
    const float* __restrict__ hw2m, int E_) {
  const int e = blockIdx.x * 4 + (threadIdx.x >> 6);
  const int l = threadIdx.x & 63;
  if (e >= E_) return;
  const int c1 = eidx[e], c2 = eidx[E_ + e];
  float p = Q2[c1 * 64 + l] * K2[c2 * 64 + l];
#pragma unroll
  for (int mk = 32; mk >= 1; mk >>= 1) p += __shfl_xor(p, mk);
  float s = p * 0.125f;
  s = s >= 0.f ? s : 0.2f * s;
  float a = hw2m[0] / (1.f + __expf(-s));
  float val = V2[c2 * 64 + l] * a;
#pragma unroll
  for (int t = 0; t < 8; ++t) {
    int row = shv[e * 8 + t];
    atomicAdd(xv + (size_t)row * 64 + l, val);
  }
}

// ---- column sums of x_var / x_clause ---------------------------------------
__global__ __launch_bounds__(256) void kSum(
    const float* __restrict__ xv, const float* __restrict__ xc,
    float* __restrict__ sums, int N, int M) {
  __shared__ float red[4][128];
  const int tid = threadIdx.x, w = tid >> 6, l = tid & 63;
  const int gw = (blockIdx.x * 256 + tid) >> 6;
  const int nw = (gridDim.x * 256) >> 6;
  float aV = 0.f, aC = 0.f;
  for (int r = gw; r < N + M; r += nw) {
    if (r < N) aV += xv[(size_t)r * 64 + l];
    else aC += xc[(size_t)(r - N) * 64 + l];
  }
  red[w][l] = aV; red[w][64 + l] = aC;
  __syncthreads();
  if (tid < 128) {
    float v = red[0][tid] + red[1][tid] + red[2][tid] + red[3][tid];
    atomicAdd(&sums[tid], v);
  }
}

// ---- pooled -> MLP -> scalar ------------------------------------------------
__global__ __launch_bounds__(128) void kMlp(
    const float* __restrict__ sums, const float* __restrict__ W1,
    const float* __restrict__ b1, const float* __restrict__ W2,
    const float* __restrict__ b2, float* __restrict__ outp, int N, int M) {
  __shared__ float pooled[128];
  __shared__ float hs[64];
  const int t = threadIdx.x;
  pooled[t] = tanhf(sums[t] * (t < 64 ? 1.f / (float)N : 1.f / (float)M));
  __syncthreads();
  if (t < 64) {
    float a = b1[t];
#pragma unroll 8
    for (int j = 0; j < 128; ++j) a += W1[t * 128 + j] * pooled[j];
    hs[t] = fmaxf(a, 0.f);
  }
  __syncthreads();
  if (t < 64) {
    float v = W2[t] * hs[t];
#pragma unroll
    for (int mk = 32; mk >= 1; mk >>= 1) v += __shfl_xor(v, mk);
    if (t == 0) outp[0] = v + b2[0];
  }
}

// ---- precompute: B^T (stored [e][d]), hw1*WV, Wo (hi/lo bf16),
//      W*2 transposes, hw2 mean --------------------------------------------
__global__ __launch_bounds__(256) void kPrep(
    const float* __restrict__ WQ1, const float* __restrict__ WK1,
    const float* __restrict__ WV1, const float* __restrict__ hw1,
    const float* __restrict__ Wo, const float* __restrict__ WQ2,
    const float* __restrict__ WK2, const float* __restrict__ WV2,
    const float* __restrict__ hw2, unsigned short* __restrict__ Bt,
    unsigned short* __restrict__ WVb, unsigned short* __restrict__ WoB,
    float* __restrict__ WQ2T, float* __restrict__ WK2T,
    float* __restrict__ WV2T, float* __restrict__ hw2m) {
  __shared__ float Qs[64][65];
  __shared__ float Ks[64][65];
  const int t = threadIdx.x;
  for (int i = t; i < 4096; i += 256) {
    Qs[i >> 6][i & 63] = WQ1[i];
    Ks[i >> 6][i & 63] = WK1[i];
  }
  const float h1m = 0.25f * (hw1[0] + hw1[1] + hw1[2] + hw1[3]);
  __syncthreads();
  for (int o = t; o < 4096; o += 256) {
    const int eo = o >> 6, d = o & 63;
    float acc = 0.f;
#pragma unroll 8
    for (int a2 = 0; a2 < 64; ++a2) acc += Qs[a2][d] * Ks[a2][eo];
    acc *= 0.125f;  // /sqrt(64)
    unsigned short hi = f2b(acc);
    Bt[o] = hi; Bt[4096 + o] = f2b(acc - b2f(hi));
    float wv = WV1[o] * h1m;
    hi = f2b(wv); WVb[o] = hi; WVb[4096 + o] = f2b(wv - b2f(hi));
    float wo = Wo[o];
    hi = f2b(wo); WoB[o] = hi; WoB[4096 + o] = f2b(wo - b2f(hi));
    const int tr = ((o & 63) << 6) | (o >> 6);
    WQ2T[o] = WQ2[tr]; WK2T[o] = WK2[tr]; WV2T[o] = WV2[tr];
  }
  if (t == 0) hw2m[0] = 0.25f * (hw2[0] + hw2[1] + hw2[2] + hw2[3]);
}

// ---- node occurrence counts (static across iterations) ---------------------
__global__ __launch_bounds__(256) void kCnt(
    const int* __restrict__ cvar, const int* __restrict__ ccla,
    float* __restrict__ cnt, int C_, int N) {
  int i = blockIdx.x * 256 + threadIdx.x;
  const int T = C_ * 192;
  for (; i < T; i += gridDim.x * 256) {
    int c = i / 192, p = i - c * 192;
    int node = (p < 64) ? cvar[c * 64 + p] : (N + ccla[c * 128 + (p - 64)]);
    atomicAdd(cnt + node, 1.0f);
  }
}

extern "C" void kernel_launch(void* const* d_in, const int* in_sizes, int n_in,
                              void* d_out, int out_size, void* d_ws, size_t ws_size,
                              hipStream_t stream) {
  (void)n_in; (void)out_size;
  float* xv = (float*)d_in[0];
  float* xc = (float*)d_in[1];
  const float* sat = (const float*)d_in[2];
  const int* cvar = (const int*)d_in[3];
  const int* ccla = (const int*)d_in[4];
  const int* eidx = (const int*)d_in[5];
  const int* shv = (const int*)d_in[6];
  const float* WQ1 = (const float*)d_in[7];
  const float* WK1 = (const float*)d_in[8];
  const float* WV1 = (const float*)d_in[9];
  const float* hw1 = (const float*)d_in[10];
  const float* Wo = (const float*)d_in[11];
  const float* bo = (const float*)d_in[12];
  const float* WQ2 = (const float*)d_in[13];
  const float* WK2 = (const float*)d_in[14];
  const float* WV2 = (const float*)d_in[15];
  const float* hw2 = (const float*)d_in[16];
  const float* W1 = (const float*)d_in[17];
  const float* b1 = (const float*)d_in[18];
  const float* W2 = (const float*)d_in[19];
  const float* b2 = (const float*)d_in[20];

  const int N = in_sizes[0] / 64;
  const int M = in_sizes[1] / 64;
  const int C = in_sizes[3] / 64;
  const int E = in_sizes[5] / 2;
  const int NM = N + M;

  // Workspace guard: undersized d_ws -> no-op (clean failure, no OOB fault).
  size_t need = 0;
  auto sz = [&](size_t bytes) { need += (bytes + 255) & ~(size_t)255; };
  sz((size_t)NM * 64 * 4);  // outb
  sz((size_t)NM * 4);       // cnt
  sz(2 * 4096 * 2); sz(2 * 4096 * 2); sz(2 * 4096 * 2);   // Bt, WVb, WoB
  sz(4096 * 4); sz(4096 * 4); sz(4096 * 4);               // WQ2T, WK2T, WV2T
  sz((size_t)C * 64 * 4); sz((size_t)C * 64 * 4); sz((size_t)C * 64 * 4);
  sz(128 * 4); sz(256);                                   // sums, hw2m
  if (need > ws_size) return;

  char* p = (char*)d_ws;
  auto alloc = [&](size_t bytes) -> void* {
    void* r = (void*)p;
    p += (bytes + 255) & ~(size_t)255;
    return r;
  };
  float* outb = (float*)alloc((size_t)NM * 64 * 4);
  float* cnt = (float*)alloc((size_t)NM * 4);
  unsigned short* Bt = (unsigned short*)alloc(2 * 4096 * 2);
  unsigned short* WVb = (unsigned short*)alloc(2 * 4096 * 2);
  unsigned short* WoB = (unsigned short*)alloc(2 * 4096 * 2);
  float* WQ2T = (float*)alloc(4096 * 4);
  float* WK2T = (float*)alloc(4096 * 4);
  float* WV2T = (float*)alloc(4096 * 4);
  float* Q2 = (float*)alloc((size_t)C * 64 * 4);
  float* K2 = (float*)alloc((size_t)C * 64 * 4);
  float* V2 = (float*)alloc((size_t)C * 64 * 4);
  float* sums = (float*)alloc(128 * 4);
  float* hw2m = (float*)alloc(256);

  hipMemsetAsync(outb, 0, (size_t)NM * 64 * 4, stream);
  hipMemsetAsync(cnt, 0, (size_t)NM * 4, stream);
  hipMemsetAsync(sums, 0, 128 * 4, stream);

  kPrep<<<1, 256, 0, stream>>>(WQ1, WK1, WV1, hw1, Wo, WQ2, WK2, WV2, hw2,
                               Bt, WVb, WoB, WQ2T, WK2T, WV2T, hw2m);
  kCnt<<<256, 256, 0, stream>>>(cvar, ccla, cnt, C, N);

  for (int it = 0; it < 3; ++it) {
    kAttn<<<C, 256, 0, stream>>>(xv, xc, sat, cvar, ccla, Bt, WVb, outb, N, M);
    kUpd<<<(NM + 127) / 128, 256, 0, stream>>>(xv, xc, bo, WoB, outb, cnt, NM, N);
    kCf<<<C, 64, 0, stream>>>(xv, cvar, WQ2T, WK2T, WV2T, Q2, K2, V2);
    kEdge<<<(E + 3) / 4, 256, 0, stream>>>(xv, Q2, K2, V2, eidx, shv, hw2m, E);
  }

  kSum<<<1024, 256, 0, stream>>>(xv, xc, sums, N, M);
  kMlp<<<1, 128, 0, stream>>>(sums, W1, b1, W2, b2, (float*)d_out, N, M);
}